// Round 1
// baseline (152.582 us; speedup 1.0000x reference)
//
#include <hip/hip_runtime.h>

typedef unsigned short u16;
typedef __attribute__((ext_vector_type(8))) short bf16x8;
typedef __attribute__((ext_vector_type(4))) float f32x4;

#define NB 64
#define NT 1024
#define NO 128
#define ND 128

__device__ __forceinline__ u16 f2bf(float f) {
    union { float f; unsigned u; } v; v.f = f;
    unsigned r = v.u + 0x7FFFu + ((v.u >> 16) & 1u);
    return (u16)(r >> 16);
}

// load 8 consecutive fp32 and convert to a bf16x8 MFMA fragment
__device__ __forceinline__ bf16x8 frag_from_f32(const float* p) {
    const float4 a = *reinterpret_cast<const float4*>(p);
    const float4 b = *reinterpret_cast<const float4*>(p + 4);
    bf16x8 r;
    r[0] = (short)f2bf(a.x); r[1] = (short)f2bf(a.y);
    r[2] = (short)f2bf(a.z); r[3] = (short)f2bf(a.w);
    r[4] = (short)f2bf(b.x); r[5] = (short)f2bf(b.y);
    r[6] = (short)f2bf(b.z); r[7] = (short)f2bf(b.w);
    return r;
}

// ---------------------------------------------------------------------------
// attn fp32 [B][T][O] -> attnT bf16 [B][O][T]
__global__ void k_transpose_attn(const float* __restrict__ attn, u16* __restrict__ attnT) {
    __shared__ float tile[32][33];
    int bid = blockIdx.x;
    int ot = bid & 3;            // O/32 = 4
    int tt = (bid >> 2) & 31;    // T/32 = 32
    int b  = bid >> 7;
    int t0 = tt * 32, o0 = ot * 32;
    int tx = threadIdx.x & 31, ty = threadIdx.x >> 5;  // ty 0..7
    const float* src = attn + ((size_t)b * NT + t0) * NO + o0;
#pragma unroll
    for (int i = 0; i < 4; i++) {
        int r = ty + i * 8;
        tile[r][tx] = src[(size_t)r * NO + tx];
    }
    __syncthreads();
    u16* dst = attnT + ((size_t)b * NO + o0) * NT + t0;
#pragma unroll
    for (int i = 0; i < 4; i++) {
        int r = ty + i * 8;
        dst[(size_t)r * NT + tx] = f2bf(tile[tx][r]);
    }
}

// ---------------------------------------------------------------------------
// Transpose+cast the 4 weight matrices: W[k][n] fp32 -> WT[n][k] bf16
__global__ void k_prep_weights(const float* __restrict__ Wmo, const float* __restrict__ Wmt,
                               const float* __restrict__ Wut, const float* __restrict__ Wuo,
                               u16* __restrict__ WmoT, u16* __restrict__ WmtT,
                               u16* __restrict__ WutT, u16* __restrict__ WuoT) {
    int idx = blockIdx.x * 256 + threadIdx.x;
    if (idx < 16384) {
        int k = idx >> 7, n = idx & 127;
        WmoT[n * 128 + k] = f2bf(Wmo[idx]);
    } else if (idx < 32768) {
        int i = idx - 16384; int k = i >> 7, n = i & 127;
        WmtT[n * 128 + k] = f2bf(Wmt[i]);
    } else if (idx < 65536) {
        int i = idx - 32768; int k = i >> 7, n = i & 127;   // Wut is [256][128]
        WutT[n * 256 + k] = f2bf(Wut[i]);
    } else if (idx < 98304) {
        int i = idx - 65536; int k = i >> 7, n = i & 127;
        WuoT[n * 256 + k] = f2bf(Wuo[i]);
    }
}

// ---------------------------------------------------------------------------
// msg_tT[b][n][t] = (tok[b] @ Wmt + bmt)^T   (blocks 0..1023)
// msg_oT[b][n][o] = (obj[b] @ Wmo + bmo)^T   (blocks 1024..1151)
__global__ void k_msg(const float* __restrict__ tok, const float* __restrict__ obj,
                      const u16* __restrict__ WmtT, const u16* __restrict__ WmoT,
                      const float* __restrict__ bmt, const float* __restrict__ bmo,
                      u16* __restrict__ msg_tT, u16* __restrict__ msg_oT) {
    int bid = blockIdx.x;
    bool is_t = bid < 1024;
    int l = threadIdx.x & 63, w = threadIdx.x >> 6;
    int l15 = l & 15, lk = (l >> 4) * 8, rsub = (l >> 4) * 4;
    const float* X; const u16* WT; const float* bias; int rows_base;
    if (is_t) { X = tok; WT = WmtT; bias = bmt; rows_base = bid * 64; }
    else      { X = obj; WT = WmoT; bias = bmo; rows_base = (bid - 1024) * 64; }
    int row0 = rows_base + w * 16;

    f32x4 acc[8] = {};
#pragma unroll
    for (int k0 = 0; k0 < 128; k0 += 32) {
        bf16x8 a = frag_from_f32(X + (size_t)(row0 + l15) * 128 + k0 + lk);
#pragma unroll
        for (int ct = 0; ct < 8; ct++) {
            bf16x8 bfr = *reinterpret_cast<const bf16x8*>(WT + (ct * 16 + l15) * 128 + k0 + lk);
            acc[ct] = __builtin_amdgcn_mfma_f32_16x16x32_bf16(a, bfr, acc[ct], 0, 0, 0);
        }
    }
#pragma unroll
    for (int ct = 0; ct < 8; ct++) {
        int n = ct * 16 + l15;
        float bv = bias[n];
        ushort4 pk;
        pk.x = f2bf(acc[ct][0] + bv);
        pk.y = f2bf(acc[ct][1] + bv);
        pk.z = f2bf(acc[ct][2] + bv);
        pk.w = f2bf(acc[ct][3] + bv);
        int grow = row0 + rsub;   // first of 4 consecutive rows
        if (is_t) {
            int b = grow >> 10, t = grow & 1023;
            *reinterpret_cast<ushort4*>(msg_tT + ((size_t)(b * 128 + n) << 10) + t) = pk;
        } else {
            int b = grow >> 7, o = grow & 127;
            *reinterpret_cast<ushort4*>(msg_oT + (size_t)(b * 128 + n) * 128 + o) = pk;
        }
    }
}

// ---------------------------------------------------------------------------
// Token side: agg = attn[b,rows] @ msg_o[b]; new_t = LN(tok + relu([tok,agg]@Wut + but))
__global__ void k_token_update(const float* __restrict__ tok, const float* __restrict__ attn,
                               const u16* __restrict__ msg_oT, const u16* __restrict__ WutT,
                               const float* __restrict__ bupd, const float* __restrict__ g,
                               const float* __restrict__ beta, float* __restrict__ out) {
    __shared__ u16 agg_lds[64][136];
    __shared__ float out_lds[64][128];
    int bid = blockIdx.x;
    int b = bid >> 4;
    int t0 = (bid & 15) * 64;
    int l = threadIdx.x & 63, w = threadIdx.x >> 6;
    int l15 = l & 15, lk = (l >> 4) * 8, rsub = (l >> 4) * 4;
    int wrow = w * 16;

    // Phase A: agg accumulate (K = O = 128)
    f32x4 acc[8] = {};
    const float* attnp = attn + (size_t)(b * NT + t0 + wrow + l15) * NO;
    const u16* mo = msg_oT + (size_t)b * 128 * 128;
#pragma unroll
    for (int k0 = 0; k0 < 128; k0 += 32) {
        bf16x8 a = frag_from_f32(attnp + k0 + lk);
#pragma unroll
        for (int ct = 0; ct < 8; ct++) {
            bf16x8 bfr = *reinterpret_cast<const bf16x8*>(mo + (ct * 16 + l15) * 128 + k0 + lk);
            acc[ct] = __builtin_amdgcn_mfma_f32_16x16x32_bf16(a, bfr, acc[ct], 0, 0, 0);
        }
    }
    // Phase B: acc -> LDS in A-fragment layout (wave-local rows, no barrier needed)
#pragma unroll
    for (int ct = 0; ct < 8; ct++) {
        int n = ct * 16 + l15;
#pragma unroll
        for (int r = 0; r < 4; r++)
            agg_lds[wrow + rsub + r][n] = f2bf(acc[ct][r]);
    }
    // Phase C: MLP (K = 256: token part then agg part)
    f32x4 accm[8] = {};
    const float* tokp = tok + (size_t)(b * NT + t0 + wrow + l15) * ND;
#pragma unroll
    for (int k0 = 0; k0 < 128; k0 += 32) {
        bf16x8 a = frag_from_f32(tokp + k0 + lk);
#pragma unroll
        for (int ct = 0; ct < 8; ct++) {
            bf16x8 bfr = *reinterpret_cast<const bf16x8*>(WutT + (ct * 16 + l15) * 256 + k0 + lk);
            accm[ct] = __builtin_amdgcn_mfma_f32_16x16x32_bf16(a, bfr, accm[ct], 0, 0, 0);
        }
    }
#pragma unroll
    for (int k0 = 0; k0 < 128; k0 += 32) {
        bf16x8 a = *reinterpret_cast<const bf16x8*>(&agg_lds[wrow + l15][k0 + lk]);
#pragma unroll
        for (int ct = 0; ct < 8; ct++) {
            bf16x8 bfr = *reinterpret_cast<const bf16x8*>(WutT + (ct * 16 + l15) * 256 + 128 + k0 + lk);
            accm[ct] = __builtin_amdgcn_mfma_f32_16x16x32_bf16(a, bfr, accm[ct], 0, 0, 0);
        }
    }
    // Phase D: residual + bias + relu -> out_lds (fp32)
#pragma unroll
    for (int ct = 0; ct < 8; ct++) {
        int n = ct * 16 + l15;
        float bv = bupd[n];
#pragma unroll
        for (int r = 0; r < 4; r++) {
            int lr = wrow + rsub + r;
            float v = tok[(size_t)(b * NT + t0 + lr) * ND + n] + fmaxf(accm[ct][r] + bv, 0.f);
            out_lds[lr][n] = v;
        }
    }
    // Phase E: LayerNorm (wave-local 16 rows)
    for (int r = 0; r < 16; r++) {
        int lr = wrow + r;
        float e0 = out_lds[lr][l], e1 = out_lds[lr][l + 64];
        float s = e0 + e1, sq = e0 * e0 + e1 * e1;
#pragma unroll
        for (int ofs = 32; ofs >= 1; ofs >>= 1) {
            s  += __shfl_xor(s, ofs, 64);
            sq += __shfl_xor(sq, ofs, 64);
        }
        float mu = s * (1.f / 128.f);
        float var = sq * (1.f / 128.f) - mu * mu;
        float rstd = rsqrtf(var + 1e-5f);
        size_t base = (size_t)(b * NT + t0 + lr) * ND;
        out[base + l]      = (e0 - mu) * rstd * g[l]      + beta[l];
        out[base + l + 64] = (e1 - mu) * rstd * g[l + 64] + beta[l + 64];
    }
}

// ---------------------------------------------------------------------------
// Object side: agg = attn^T[b,rows] @ msg_t[b] (K=1024); fused MLP + LN
__global__ void k_obj_update(const float* __restrict__ obj, const u16* __restrict__ attnT,
                             const u16* __restrict__ msg_tT, const u16* __restrict__ WuoT,
                             const float* __restrict__ bupd, const float* __restrict__ g,
                             const float* __restrict__ beta, float* __restrict__ out) {
    __shared__ u16 agg_lds[64][136];
    __shared__ float out_lds[64][128];
    int bid = blockIdx.x;
    int b = bid >> 1;
    int o0 = (bid & 1) * 64;
    int l = threadIdx.x & 63, w = threadIdx.x >> 6;
    int l15 = l & 15, lk = (l >> 4) * 8, rsub = (l >> 4) * 4;
    int wrow = w * 16;

    // Phase A: agg (K = T = 1024)
    f32x4 acc[8] = {};
    const u16* ap = attnT + (size_t)(b * NO + o0 + wrow + l15) * NT;
    const u16* mp = msg_tT + (size_t)b * 128 * 1024;
#pragma unroll 4
    for (int k0 = 0; k0 < 1024; k0 += 32) {
        bf16x8 a = *reinterpret_cast<const bf16x8*>(ap + k0 + lk);
#pragma unroll
        for (int ct = 0; ct < 8; ct++) {
            bf16x8 bfr = *reinterpret_cast<const bf16x8*>(mp + ((size_t)(ct * 16 + l15) << 10) + k0 + lk);
            acc[ct] = __builtin_amdgcn_mfma_f32_16x16x32_bf16(a, bfr, acc[ct], 0, 0, 0);
        }
    }
    // Phase B: acc -> LDS (A layout)
#pragma unroll
    for (int ct = 0; ct < 8; ct++) {
        int n = ct * 16 + l15;
#pragma unroll
        for (int r = 0; r < 4; r++)
            agg_lds[wrow + rsub + r][n] = f2bf(acc[ct][r]);
    }
    // Phase C: MLP (K = 256)
    f32x4 accm[8] = {};
    const float* objp = obj + (size_t)(b * NO + o0 + wrow + l15) * ND;
#pragma unroll
    for (int k0 = 0; k0 < 128; k0 += 32) {
        bf16x8 a = frag_from_f32(objp + k0 + lk);
#pragma unroll
        for (int ct = 0; ct < 8; ct++) {
            bf16x8 bfr = *reinterpret_cast<const bf16x8*>(WuoT + (ct * 16 + l15) * 256 + k0 + lk);
            accm[ct] = __builtin_amdgcn_mfma_f32_16x16x32_bf16(a, bfr, accm[ct], 0, 0, 0);
        }
    }
#pragma unroll
    for (int k0 = 0; k0 < 128; k0 += 32) {
        bf16x8 a = *reinterpret_cast<const bf16x8*>(&agg_lds[wrow + l15][k0 + lk]);
#pragma unroll
        for (int ct = 0; ct < 8; ct++) {
            bf16x8 bfr = *reinterpret_cast<const bf16x8*>(WuoT + (ct * 16 + l15) * 256 + 128 + k0 + lk);
            accm[ct] = __builtin_amdgcn_mfma_f32_16x16x32_bf16(a, bfr, accm[ct], 0, 0, 0);
        }
    }
    // Phase D: residual + relu -> out_lds
#pragma unroll
    for (int ct = 0; ct < 8; ct++) {
        int n = ct * 16 + l15;
        float bv = bupd[n];
#pragma unroll
        for (int r = 0; r < 4; r++) {
            int lr = wrow + rsub + r;
            float v = obj[(size_t)(b * NO + o0 + lr) * ND + n] + fmaxf(accm[ct][r] + bv, 0.f);
            out_lds[lr][n] = v;
        }
    }
    // Phase E: LayerNorm
    for (int r = 0; r < 16; r++) {
        int lr = wrow + r;
        float e0 = out_lds[lr][l], e1 = out_lds[lr][l + 64];
        float s = e0 + e1, sq = e0 * e0 + e1 * e1;
#pragma unroll
        for (int ofs = 32; ofs >= 1; ofs >>= 1) {
            s  += __shfl_xor(s, ofs, 64);
            sq += __shfl_xor(sq, ofs, 64);
        }
        float mu = s * (1.f / 128.f);
        float var = sq * (1.f / 128.f) - mu * mu;
        float rstd = rsqrtf(var + 1e-5f);
        size_t base = (size_t)(b * NO + o0 + lr) * ND;
        out[base + l]      = (e0 - mu) * rstd * g[l]      + beta[l];
        out[base + l + 64] = (e1 - mu) * rstd * g[l + 64] + beta[l + 64];
    }
}

// ---------------------------------------------------------------------------
extern "C" void kernel_launch(void* const* d_in, const int* in_sizes, int n_in,
                              void* d_out, int out_size, void* d_ws, size_t ws_size,
                              hipStream_t stream) {
    const float* tok  = (const float*)d_in[0];
    const float* obj  = (const float*)d_in[1];
    const float* attn = (const float*)d_in[2];
    const float* Wmo  = (const float*)d_in[3];
    const float* bmo  = (const float*)d_in[4];
    const float* Wmt  = (const float*)d_in[5];
    const float* bmt  = (const float*)d_in[6];
    const float* Wut  = (const float*)d_in[7];
    const float* but  = (const float*)d_in[8];
    const float* Wuo  = (const float*)d_in[9];
    const float* buo  = (const float*)d_in[10];
    const float* gt   = (const float*)d_in[11];
    const float* bt   = (const float*)d_in[12];
    const float* go   = (const float*)d_in[13];
    const float* bo   = (const float*)d_in[14];
    float* out = (float*)d_out;

    u16* ws = (u16*)d_ws;
    u16* attnT  = ws;                      // 64*128*1024 = 8388608
    u16* msg_tT = attnT + 8388608;         // 8388608
    u16* msg_oT = msg_tT + 8388608;        // 64*128*128 = 1048576
    u16* WmoT   = msg_oT + 1048576;        // 16384
    u16* WmtT   = WmoT + 16384;            // 16384
    u16* WutT   = WmtT + 16384;            // 32768
    u16* WuoT   = WutT + 32768;            // 32768

    k_transpose_attn<<<dim3(8192), dim3(256), 0, stream>>>(attn, attnT);
    k_prep_weights<<<dim3(384), dim3(256), 0, stream>>>(Wmo, Wmt, Wut, Wuo, WmoT, WmtT, WutT, WuoT);
    k_msg<<<dim3(1152), dim3(256), 0, stream>>>(tok, obj, WmtT, WmoT, bmt, bmo, msg_tT, msg_oT);
    k_token_update<<<dim3(1024), dim3(256), 0, stream>>>(tok, attn, msg_oT, WutT, but, gt, bt, out);
    k_obj_update<<<dim3(128), dim3(256), 0, stream>>>(obj, attnT, msg_tT, WuoT, buo, go, bo,
                                                      out + (size_t)NB * NT * ND);
}

// Round 3
// 132.976 us; speedup vs baseline: 1.1474x; 1.1474x over previous
//
#include <hip/hip_runtime.h>

typedef unsigned short u16;
typedef __attribute__((ext_vector_type(8))) short bf16x8;
typedef __attribute__((ext_vector_type(4))) float f32x4;

#define NB 64
#define NT 1024
#define NO 128
#define ND 128

__device__ __forceinline__ u16 f2bf(float f) {
    union { float f; unsigned u; } v; v.f = f;
    unsigned r = v.u + 0x7FFFu + ((v.u >> 16) & 1u);
    return (u16)(r >> 16);
}

// load 8 consecutive fp32 and convert to a bf16x8 MFMA fragment
__device__ __forceinline__ bf16x8 frag_from_f32(const float* p) {
    const float4 a = *reinterpret_cast<const float4*>(p);
    const float4 b = *reinterpret_cast<const float4*>(p + 4);
    bf16x8 r;
    r[0] = (short)f2bf(a.x); r[1] = (short)f2bf(a.y);
    r[2] = (short)f2bf(a.z); r[3] = (short)f2bf(a.w);
    r[4] = (short)f2bf(b.x); r[5] = (short)f2bf(b.y);
    r[6] = (short)f2bf(b.z); r[7] = (short)f2bf(b.w);
    return r;
}

// ---------------------------------------------------------------------------
// attn fp32 [B][T][O] -> attnT bf16 [B][O][T]
__global__ void k_transpose_attn(const float* __restrict__ attn, u16* __restrict__ attnT) {
    __shared__ float tile[32][33];
    int bid = blockIdx.x;
    int ot = bid & 3;            // O/32 = 4
    int tt = (bid >> 2) & 31;    // T/32 = 32
    int b  = bid >> 7;
    int t0 = tt * 32, o0 = ot * 32;
    int tx = threadIdx.x & 31, ty = threadIdx.x >> 5;  // ty 0..7
    const float* src = attn + ((size_t)b * NT + t0) * NO + o0;
#pragma unroll
    for (int i = 0; i < 4; i++) {
        int r = ty + i * 8;
        tile[r][tx] = src[(size_t)r * NO + tx];
    }
    __syncthreads();
    u16* dst = attnT + ((size_t)b * NO + o0) * NT + t0;
#pragma unroll
    for (int i = 0; i < 4; i++) {
        int r = ty + i * 8;
        dst[(size_t)r * NT + tx] = f2bf(tile[tx][r]);
    }
}

// ---------------------------------------------------------------------------
// Transpose+cast the 4 weight matrices: W[k][n] fp32 -> WT[n][k] bf16
__global__ void k_prep_weights(const float* __restrict__ Wmo, const float* __restrict__ Wmt,
                               const float* __restrict__ Wut, const float* __restrict__ Wuo,
                               u16* __restrict__ WmoT, u16* __restrict__ WmtT,
                               u16* __restrict__ WutT, u16* __restrict__ WuoT) {
    int idx = blockIdx.x * 256 + threadIdx.x;
    if (idx < 16384) {
        int k = idx >> 7, n = idx & 127;
        WmoT[n * 128 + k] = f2bf(Wmo[idx]);
    } else if (idx < 32768) {
        int i = idx - 16384; int k = i >> 7, n = i & 127;
        WmtT[n * 128 + k] = f2bf(Wmt[i]);
    } else if (idx < 65536) {
        int i = idx - 32768; int k = i >> 7, n = i & 127;   // Wut is [256][128]
        WutT[n * 256 + k] = f2bf(Wut[i]);
    } else if (idx < 98304) {
        int i = idx - 65536; int k = i >> 7, n = i & 127;
        WuoT[n * 256 + k] = f2bf(Wuo[i]);
    }
}

// ---------------------------------------------------------------------------
// msg_tT[b][n][t] = (tok[b] @ Wmt + bmt)^T   (blocks 0..1023)
// msg_oT[b][n][o] = (obj[b] @ Wmo + bmo)^T   (blocks 1024..1151)
// Output restaged through LDS so global writes are coalesced 128B rows.
__global__ void k_msg(const float* __restrict__ tok, const float* __restrict__ obj,
                      const u16* __restrict__ WmtT, const u16* __restrict__ WmoT,
                      const float* __restrict__ bmt, const float* __restrict__ bmo,
                      u16* __restrict__ msg_tT, u16* __restrict__ msg_oT) {
    __shared__ u16 lds_m[128][72];   // [n][row_local], 16B-aligned rows (144B stride)
    int bid = blockIdx.x;
    bool is_t = bid < 1024;
    int l = threadIdx.x & 63, w = threadIdx.x >> 6;
    int l15 = l & 15, lk = (l >> 4) * 8, rsub = (l >> 4) * 4;
    const float* X; const u16* WT; const float* bias; int rows_base;
    if (is_t) { X = tok; WT = WmtT; bias = bmt; rows_base = bid * 64; }
    else      { X = obj; WT = WmoT; bias = bmo; rows_base = (bid - 1024) * 64; }
    int wrow = w * 16;
    int row0 = rows_base + wrow;

    f32x4 acc[8] = {};
#pragma unroll
    for (int k0 = 0; k0 < 128; k0 += 32) {
        bf16x8 a = frag_from_f32(X + (size_t)(row0 + l15) * 128 + k0 + lk);
#pragma unroll
        for (int ct = 0; ct < 8; ct++) {
            bf16x8 bfr = *reinterpret_cast<const bf16x8*>(WT + (ct * 16 + l15) * 128 + k0 + lk);
            acc[ct] = __builtin_amdgcn_mfma_f32_16x16x32_bf16(a, bfr, acc[ct], 0, 0, 0);
        }
    }
#pragma unroll
    for (int ct = 0; ct < 8; ct++) {
        int n = ct * 16 + l15;
        float bv = bias[n];
        ushort4 pk;
        pk.x = f2bf(acc[ct][0] + bv);
        pk.y = f2bf(acc[ct][1] + bv);
        pk.z = f2bf(acc[ct][2] + bv);
        pk.w = f2bf(acc[ct][3] + bv);
        *reinterpret_cast<ushort4*>(&lds_m[n][wrow + rsub]) = pk;  // 4 consecutive local rows
    }
    __syncthreads();
    // coalesced write-out: thread -> (n = tid>>1, half = tid&1), 64B each
    int n = threadIdx.x >> 1, h = threadIdx.x & 1;
    const u16* src = &lds_m[n][h * 32];
    u16* dst;
    if (is_t) {
        int b = rows_base >> 10, t0 = rows_base & 1023;
        dst = msg_tT + ((size_t)(b * 128 + n) << 10) + t0 + h * 32;
    } else {
        int b = rows_base >> 7, o0 = rows_base & 127;
        dst = msg_oT + (size_t)(b * 128 + n) * 128 + o0 + h * 32;
    }
#pragma unroll
    for (int i = 0; i < 4; i++)
        *reinterpret_cast<bf16x8*>(dst + i * 8) = *reinterpret_cast<const bf16x8*>(src + i * 8);
}

// ---------------------------------------------------------------------------
// Token side: agg = attn[b,rows] @ msg_o[b]; new_t = LN(tok + relu([tok,agg]@Wut + but))
// LayerNorm fully in registers (C-layout row = 16 lanes x 8 regs).
__global__ void k_token_update(const float* __restrict__ tok, const float* __restrict__ attn,
                               const u16* __restrict__ msg_oT, const u16* __restrict__ WutT,
                               const float* __restrict__ bupd, const float* __restrict__ g,
                               const float* __restrict__ beta, float* __restrict__ out) {
    __shared__ u16 agg_lds[64][136];   // [row][128 cols + 8 pad] = 17.4 KB
    int bid = blockIdx.x;
    int b = bid >> 4;
    int t0 = (bid & 15) * 64;
    int l = threadIdx.x & 63, w = threadIdx.x >> 6;
    int l15 = l & 15, lk = (l >> 4) * 8, rsub = (l >> 4) * 4;
    int wrow = w * 16;

    // Phase A: agg accumulate (K = O = 128)
    f32x4 acc[8] = {};
    const float* attnp = attn + (size_t)(b * NT + t0 + wrow + l15) * NO;
    const u16* mo = msg_oT + (size_t)b * 128 * 128;
#pragma unroll
    for (int k0 = 0; k0 < 128; k0 += 32) {
        bf16x8 a = frag_from_f32(attnp + k0 + lk);
#pragma unroll
        for (int ct = 0; ct < 8; ct++) {
            bf16x8 bfr = *reinterpret_cast<const bf16x8*>(mo + (ct * 16 + l15) * 128 + k0 + lk);
            acc[ct] = __builtin_amdgcn_mfma_f32_16x16x32_bf16(a, bfr, acc[ct], 0, 0, 0);
        }
    }
    // Phase B: acc -> LDS in A-fragment layout (wave-local rows, no barrier needed)
#pragma unroll
    for (int ct = 0; ct < 8; ct++) {
        int n = ct * 16 + l15;
#pragma unroll
        for (int r = 0; r < 4; r++)
            agg_lds[wrow + rsub + r][n] = f2bf(acc[ct][r]);
    }
    // Phase C: MLP (K = 256: token part then agg part)
    f32x4 accm[8] = {};
    const float* tokp = tok + (size_t)(b * NT + t0 + wrow + l15) * ND;
#pragma unroll
    for (int k0 = 0; k0 < 128; k0 += 32) {
        bf16x8 a = frag_from_f32(tokp + k0 + lk);
#pragma unroll
        for (int ct = 0; ct < 8; ct++) {
            bf16x8 bfr = *reinterpret_cast<const bf16x8*>(WutT + (ct * 16 + l15) * 256 + k0 + lk);
            accm[ct] = __builtin_amdgcn_mfma_f32_16x16x32_bf16(a, bfr, accm[ct], 0, 0, 0);
        }
    }
#pragma unroll
    for (int k0 = 0; k0 < 128; k0 += 32) {
        bf16x8 a = *reinterpret_cast<const bf16x8*>(&agg_lds[wrow + l15][k0 + lk]);
#pragma unroll
        for (int ct = 0; ct < 8; ct++) {
            bf16x8 bfr = *reinterpret_cast<const bf16x8*>(WutT + (ct * 16 + l15) * 256 + 128 + k0 + lk);
            accm[ct] = __builtin_amdgcn_mfma_f32_16x16x32_bf16(a, bfr, accm[ct], 0, 0, 0);
        }
    }
    // Phase D: residual + bias + relu (in regs) + per-row partial sums
    const float* tokr = tok + (size_t)(b * NT + t0) * ND;
    float s[4] = {0.f, 0.f, 0.f, 0.f}, sq[4] = {0.f, 0.f, 0.f, 0.f};
#pragma unroll
    for (int ct = 0; ct < 8; ct++) {
        int n = ct * 16 + l15;
        float bv = bupd[n];
#pragma unroll
        for (int r = 0; r < 4; r++) {
            int lr = wrow + rsub + r;
            float v = tokr[(size_t)lr * ND + n] + fmaxf(accm[ct][r] + bv, 0.f);
            accm[ct][r] = v;
            s[r] += v;
            sq[r] += v * v;
        }
    }
    // Phase E: 16-lane reduce (each 16-lane group owns its 4 rows)
#pragma unroll
    for (int ofs = 1; ofs < 16; ofs <<= 1) {
#pragma unroll
        for (int r = 0; r < 4; r++) {
            s[r]  += __shfl_xor(s[r], ofs, 64);
            sq[r] += __shfl_xor(sq[r], ofs, 64);
        }
    }
    float mu[4], rstd[4];
#pragma unroll
    for (int r = 0; r < 4; r++) {
        mu[r] = s[r] * (1.f / 128.f);
        float var = sq[r] * (1.f / 128.f) - mu[r] * mu[r];
        rstd[r] = rsqrtf(var + 1e-5f);
    }
#pragma unroll
    for (int ct = 0; ct < 8; ct++) {
        int n = ct * 16 + l15;
        float gn = g[n], bn = beta[n];
#pragma unroll
        for (int r = 0; r < 4; r++) {
            int lr = wrow + rsub + r;
            out[(size_t)(b * NT + t0 + lr) * ND + n] = (accm[ct][r] - mu[r]) * rstd[r] * gn + bn;
        }
    }
}

// ---------------------------------------------------------------------------
// Object side: 16-row tiles, grid B*8 = 512 blocks. Wave w: cols w*32..w*32+31.
// agg = attn^T[b,rows] @ msg_t[b] (K=1024); fused MLP + LN (cross-wave partials).
__global__ void k_obj_update(const float* __restrict__ obj, const u16* __restrict__ attnT,
                             const u16* __restrict__ msg_tT, const u16* __restrict__ WuoT,
                             const float* __restrict__ bupd, const float* __restrict__ g,
                             const float* __restrict__ beta, float* __restrict__ out) {
    __shared__ u16 agg_lds[16][136];      // [row][128 cols + 8 pad]
    __shared__ float part_s[16][4], part_sq[16][4];
    int bid = blockIdx.x;
    int b = bid >> 3;
    int o0 = (bid & 7) * 16;
    int l = threadIdx.x & 63, w = threadIdx.x >> 6;
    int l15 = l & 15, lk = (l >> 4) * 8, rsub = (l >> 4) * 4;
    int ch = w * 32;   // this wave's 32 output columns

    // Phase A: agg (K = T = 1024), 2 ct tiles per wave
    f32x4 acc[2] = {};
    const u16* ap = attnT + (size_t)(b * NO + o0 + l15) * NT;
    const u16* mp = msg_tT + (size_t)b * 128 * 1024;
#pragma unroll 4
    for (int k0 = 0; k0 < 1024; k0 += 32) {
        bf16x8 a = *reinterpret_cast<const bf16x8*>(ap + k0 + lk);
#pragma unroll
        for (int ct = 0; ct < 2; ct++) {
            bf16x8 bfr = *reinterpret_cast<const bf16x8*>(mp + ((size_t)(ch + ct * 16 + l15) << 10) + k0 + lk);
            acc[ct] = __builtin_amdgcn_mfma_f32_16x16x32_bf16(a, bfr, acc[ct], 0, 0, 0);
        }
    }
    // Phase B: acc -> LDS (A layout); cross-wave (cols interleave) -> barrier
#pragma unroll
    for (int ct = 0; ct < 2; ct++) {
        int n = ch + ct * 16 + l15;
#pragma unroll
        for (int r = 0; r < 4; r++)
            agg_lds[rsub + r][n] = f2bf(acc[ct][r]);
    }
    __syncthreads();
    // Phase C: MLP (K = 256), rows o0..o0+15, this wave's 32 cols
    f32x4 accm[2] = {};
    const float* objp = obj + (size_t)(b * NO + o0 + l15) * ND;
#pragma unroll
    for (int k0 = 0; k0 < 128; k0 += 32) {
        bf16x8 a = frag_from_f32(objp + k0 + lk);
#pragma unroll
        for (int ct = 0; ct < 2; ct++) {
            bf16x8 bfr = *reinterpret_cast<const bf16x8*>(WuoT + (ch + ct * 16 + l15) * 256 + k0 + lk);
            accm[ct] = __builtin_amdgcn_mfma_f32_16x16x32_bf16(a, bfr, accm[ct], 0, 0, 0);
        }
    }
#pragma unroll
    for (int k0 = 0; k0 < 128; k0 += 32) {
        bf16x8 a = *reinterpret_cast<const bf16x8*>(&agg_lds[l15][k0 + lk]);
#pragma unroll
        for (int ct = 0; ct < 2; ct++) {
            bf16x8 bfr = *reinterpret_cast<const bf16x8*>(WuoT + (ch + ct * 16 + l15) * 256 + 128 + k0 + lk);
            accm[ct] = __builtin_amdgcn_mfma_f32_16x16x32_bf16(a, bfr, accm[ct], 0, 0, 0);
        }
    }
    // Phase D: residual + relu + column-partial LN sums
    const float* objr = obj + (size_t)(b * NO + o0) * ND;
    float s[4] = {0.f, 0.f, 0.f, 0.f}, sq[4] = {0.f, 0.f, 0.f, 0.f};
#pragma unroll
    for (int ct = 0; ct < 2; ct++) {
        int n = ch + ct * 16 + l15;
        float bv = bupd[n];
#pragma unroll
        for (int r = 0; r < 4; r++) {
            int lr = rsub + r;
            float v = objr[(size_t)lr * ND + n] + fmaxf(accm[ct][r] + bv, 0.f);
            accm[ct][r] = v;
            s[r] += v;
            sq[r] += v * v;
        }
    }
#pragma unroll
    for (int ofs = 1; ofs < 16; ofs <<= 1) {
#pragma unroll
        for (int r = 0; r < 4; r++) {
            s[r]  += __shfl_xor(s[r], ofs, 64);
            sq[r] += __shfl_xor(sq[r], ofs, 64);
        }
    }
    if (l15 < 4) {
        float sv = (l15 == 0) ? s[0] : (l15 == 1) ? s[1] : (l15 == 2) ? s[2] : s[3];
        float qv = (l15 == 0) ? sq[0] : (l15 == 1) ? sq[1] : (l15 == 2) ? sq[2] : sq[3];
        part_s[rsub + l15][w] = sv;
        part_sq[rsub + l15][w] = qv;
    }
    __syncthreads();
    // Phase E: combine partials, normalize, write
#pragma unroll
    for (int r = 0; r < 4; r++) {
        int lr = rsub + r;
        float st = part_s[lr][0] + part_s[lr][1] + part_s[lr][2] + part_s[lr][3];
        float qt = part_sq[lr][0] + part_sq[lr][1] + part_sq[lr][2] + part_sq[lr][3];
        float mu = st * (1.f / 128.f);
        float rstd = rsqrtf(qt * (1.f / 128.f) - mu * mu + 1e-5f);
#pragma unroll
        for (int ct = 0; ct < 2; ct++) {
            int n = ch + ct * 16 + l15;
            out[(size_t)(b * NO + o0 + lr) * ND + n] = (accm[ct][r] - mu) * rstd * g[n] + beta[n];
        }
    }
}

// ---------------------------------------------------------------------------
extern "C" void kernel_launch(void* const* d_in, const int* in_sizes, int n_in,
                              void* d_out, int out_size, void* d_ws, size_t ws_size,
                              hipStream_t stream) {
    const float* tok  = (const float*)d_in[0];
    const float* obj  = (const float*)d_in[1];
    const float* attn = (const float*)d_in[2];
    const float* Wmo  = (const float*)d_in[3];
    const float* bmo  = (const float*)d_in[4];
    const float* Wmt  = (const float*)d_in[5];
    const float* bmt  = (const float*)d_in[6];
    const float* Wut  = (const float*)d_in[7];
    const float* but  = (const float*)d_in[8];
    const float* Wuo  = (const float*)d_in[9];
    const float* buo  = (const float*)d_in[10];
    const float* gt   = (const float*)d_in[11];
    const float* bt   = (const float*)d_in[12];
    const float* go   = (const float*)d_in[13];
    const float* bo   = (const float*)d_in[14];
    float* out = (float*)d_out;

    u16* ws = (u16*)d_ws;
    u16* attnT  = ws;                      // 64*128*1024 = 8388608
    u16* msg_tT = attnT + 8388608;         // 8388608
    u16* msg_oT = msg_tT + 8388608;        // 64*128*128 = 1048576
    u16* WmoT   = msg_oT + 1048576;        // 16384
    u16* WmtT   = WmoT + 16384;            // 16384
    u16* WutT   = WmtT + 16384;            // 32768
    u16* WuoT   = WutT + 32768;            // 32768

    k_transpose_attn<<<dim3(8192), dim3(256), 0, stream>>>(attn, attnT);
    k_prep_weights<<<dim3(384), dim3(256), 0, stream>>>(Wmo, Wmt, Wut, Wuo, WmoT, WmtT, WutT, WuoT);
    k_msg<<<dim3(1152), dim3(256), 0, stream>>>(tok, obj, WmtT, WmoT, bmt, bmo, msg_tT, msg_oT);
    k_token_update<<<dim3(1024), dim3(256), 0, stream>>>(tok, attn, msg_oT, WutT, but, gt, bt, out);
    k_obj_update<<<dim3(512), dim3(256), 0, stream>>>(obj, attnT, msg_tT, WuoT, buo, go, bo,
                                                      out + (size_t)NB * NT * ND);
}